// Round 13
// baseline (402.318 us; speedup 1.0000x reference)
//
#include <hip/hip_runtime.h>
#include <hip/hip_bf16.h>

#define N_NODES 50000
#define M2      50048          // padded to multiple of 64
#define N_EDGES 800000
#define H 64
#define F 74
#define T 4
#define STEPS 4
#define NTILES16 (M2/16)       // 3128 wave-tiles of 16 rows
#define PAD_REC  (M2*4)        // zeroed pad row in ntr
#define SCAN_NB  196           // ceil(N_NODES/256)

using short8 = __attribute__((ext_vector_type(8))) short;
using f32x4  = __attribute__((ext_vector_type(4))) float;
typedef unsigned short ushort_t;

#define MFMA(a,b,c) __builtin_amdgcn_mfma_f32_16x16x32_bf16(a,b,c,0,0,0)

static __device__ inline float b2f(ushort_t u) {
    union { unsigned int i; float f; } c; c.i = ((unsigned int)u) << 16; return c.f;
}
static __device__ inline ushort_t f2b(float v) {
    union { __hip_bfloat16 b; ushort_t u; } c; c.b = __float2bfloat16(v); return c.u;
}
static __device__ inline void split_store(ushort_t* hi, ushort_t* lo, size_t ix, float v) {
    ushort_t h = f2b(v);
    hi[ix] = h;
    lo[ix] = f2b(v - b2f(h));
}
static __device__ inline float sigm(float x) { return 1.f / (1.f + __expf(-x)); }
static __device__ inline float tanh_f(float x) {
    float e2 = __expf(2.f * x); return 1.f - 2.f / (e2 + 1.f);
}

// ---- LDS staging of B-tiles (bf16, row-major [rows][KW8*8]) with XOR swizzle
template<int KW8>
static __device__ inline void stage_tile(const ushort_t* __restrict__ g, ushort_t* l,
                                         int rows, int tid, int nthr) {
    const int chunks = rows * KW8;
    for (int i = tid; i < chunks; i += nthr) {
        int row = i / KW8, kg = i - row * KW8;
        short8 v = *(const short8*)(g + (size_t)row * (KW8 * 8) + kg * 8);
        int b = (row * (KW8 * 16) + kg * 16) ^ ((row & 7) << 4);
        *(short8*)((char*)l + b) = v;
    }
}
template<int KW8>
static __device__ inline short8 rdfrag(const ushort_t* l, int row, int kg) {
    int b = (row * (KW8 * 16) + kg * 16) ^ ((row & 7) << 4);
    return *(const short8*)((const char*)l + b);
}
static __device__ inline short8 afrag(const ushort_t* base, int LD, int row, int kg) {
    return *(const short8*)(base + (size_t)row * LD + kg * 8);
}

// ---------------------------------------------------------------------------
// fused weight prep + deg-zero + ntr-pad-zero + x split (runs FIRST).
// ranges: [0,6144) Win | [6144,22528) E(hi) | [22528,47104) gru-hi |
//   [47104,55296) gru-lo | [55296,63488) W1 | [63488,67584) W2 |
//   [67584,117584) deg=0 | [117584,117648) ntr pad=0 | [117648,+M2*96) x split
__global__ __launch_bounds__(256) void prep_w_kernel(
    const float* __restrict__ W_in, const float* __restrict__ eW,
    const float* __restrict__ Wih, const float* __restrict__ Whh,
    const float* __restrict__ W1, const float* __restrict__ W2,
    const float* __restrict__ x,
    ushort_t* __restrict__ BtWin_hi, ushort_t* __restrict__ BtWin_lo,
    ushort_t* __restrict__ BtE_hi,
    ushort_t* __restrict__ BtgHi, ushort_t* __restrict__ BtgLo,
    ushort_t* __restrict__ BtW1_hi, ushort_t* __restrict__ BtW1_lo,
    ushort_t* __restrict__ BtW2_hi, ushort_t* __restrict__ BtW2_lo,
    int* __restrict__ deg, ushort_t* __restrict__ ntr_pad,
    ushort_t* __restrict__ x_hi, ushort_t* __restrict__ x_lo)
{
    int idx = blockIdx.x * 256 + threadIdx.x;
    if (idx < 6144) {                       // Win: [64 col][96 k]
        int col = idx / 96, k = idx - col * 96;
        float v = (k < F) ? W_in[(size_t)k * 64 + col] : 0.f;
        split_store(BtWin_hi, BtWin_lo, idx, v);
    } else if (idx < 22528) {               // E: [256 c][64 k], hi only
        int i = idx - 6144;
        int c = i >> 6, k = i & 63;
        float v = eW[(c >> 6) * 4096 + k * 64 + (c & 63)];
        BtE_hi[i] = f2b(v);
    } else if (idx < 47104) {               // gru hi: [2 half][96 row][128 k]
        int i = idx - 22528;
        int hh = i / 12288;
        int r2 = i - hh * 12288;
        int rr = r2 >> 7, k = r2 & 127;     // rr 0..95
        int gg = rr >> 5, cc = rr & 31;     // gg 0..2 (r,z,n)
        int col = gg * 64 + hh * 32 + cc;
        float v = (k < 64) ? Wih[(size_t)k * 192 + col]
                           : Whh[(size_t)(k - 64) * 192 + col];
        BtgHi[i] = f2b(v);
    } else if (idx < 55296) {               // gru lo (n gate): [2 half][32 row][128 k]
        int i = idx - 47104;
        int hh = i >> 12;
        int r2 = i & 4095;
        int cc = r2 >> 7, k = r2 & 127;
        int col = 128 + hh * 32 + cc;
        float v = (k < 64) ? Wih[(size_t)k * 192 + col]
                           : Whh[(size_t)(k - 64) * 192 + col];
        ushort_t h = f2b(v);
        BtgLo[i] = f2b(v - b2f(h));
    } else if (idx < 63488) {               // W1: [64 col][128 k]
        int i = idx - 55296;
        int col = i >> 7, k = i & 127;
        float v = W1[(size_t)k * 64 + col];
        split_store(BtW1_hi, BtW1_lo, i, v);
    } else if (idx < 67584) {               // W2: [64 col][64 k]
        int i = idx - 63488;
        int col = i >> 6, k = i & 63;
        float v = W2[(size_t)k * 64 + col];
        split_store(BtW2_hi, BtW2_lo, i, v);
    } else if (idx < 117584) {              // deg zero
        deg[idx - 67584] = 0;
    } else if (idx < 117648) {              // ntr pad row zero
        ntr_pad[idx - 117584] = 0;
    } else {                                // x split [M2][96]
        int i = idx - 117648;
        if (i < M2 * 96) {
            int row = i / 96, c = i - row * 96;
            float v = (row < N_NODES && c < F) ? x[(size_t)row * F + c] : 0.f;
            split_store(x_hi, x_lo, i, v);
        }
    }
}

// ---------------------------------------------------------------------------
// CSR build: one atomic pass (deg + rank), two-level scan, no-atomic scatter.
__global__ __launch_bounds__(256) void degrank_kernel(
    const int* __restrict__ dst, int* __restrict__ deg, int* __restrict__ rank)
{
    int e = blockIdx.x * 256 + threadIdx.x;
    if (e < N_EDGES) rank[e] = atomicAdd(&deg[dst[e]], 1);
}

__global__ __launch_bounds__(256) void scan_p1(
    const int* __restrict__ deg, int* __restrict__ bsum)
{
    __shared__ int ws4[4];
    const int tid = threadIdx.x, lane = tid & 63, w = tid >> 6;
    int idx = blockIdx.x * 256 + tid;
    int v = (idx < N_NODES) ? deg[idx] : 0;
#pragma unroll
    for (int off = 32; off >= 1; off >>= 1) v += __shfl_down(v, off, 64);
    if (lane == 0) ws4[w] = v;
    __syncthreads();
    if (tid == 0) bsum[blockIdx.x] = ws4[0] + ws4[1] + ws4[2] + ws4[3];
}

__global__ __launch_bounds__(256) void scan_p2(
    const int* __restrict__ bsum, int* __restrict__ boff, int* __restrict__ rowp)
{
    __shared__ int ws4[4];
    const int tid = threadIdx.x, lane = tid & 63, w = tid >> 6;
    int v = (tid < SCAN_NB) ? bsum[tid] : 0;
    int x = v;
#pragma unroll
    for (int off = 1; off < 64; off <<= 1) {
        int u = __shfl_up(x, off, 64);
        if (lane >= off) x += u;
    }
    if (lane == 63) ws4[w] = x;
    __syncthreads();
    int a0 = ws4[0], a1 = ws4[1], a2 = ws4[2];
    int add = (w > 0 ? a0 : 0) + (w > 1 ? a1 : 0) + (w > 2 ? a2 : 0);
    if (tid < SCAN_NB) boff[tid] = add + x - v;
    if (tid == 255) rowp[N_NODES] = add + x;
}

__global__ __launch_bounds__(256) void scan_p3(
    const int* __restrict__ deg, const int* __restrict__ boff,
    int* __restrict__ rowp)
{
    __shared__ int ws4[4];
    const int tid = threadIdx.x, lane = tid & 63, w = tid >> 6;
    int idx = blockIdx.x * 256 + tid;
    int v = (idx < N_NODES) ? deg[idx] : 0;
    int x = v;
#pragma unroll
    for (int off = 1; off < 64; off <<= 1) {
        int u = __shfl_up(x, off, 64);
        if (lane >= off) x += u;
    }
    if (lane == 63) ws4[w] = x;
    __syncthreads();
    int a0 = ws4[0], a1 = ws4[1], a2 = ws4[2];
    int add = boff[blockIdx.x]
            + (w > 0 ? a0 : 0) + (w > 1 ? a1 : 0) + (w > 2 ? a2 : 0);
    if (idx < N_NODES) rowp[idx] = add + x - v;
}

__global__ __launch_bounds__(256) void fill2_kernel(
    const int* __restrict__ src, const int* __restrict__ etype,
    const int* __restrict__ dst, const int* __restrict__ rowp,
    const int* __restrict__ rank, int* __restrict__ ss)
{
    int e = blockIdx.x * 256 + threadIdx.x;
    if (e < N_EDGES)
        ss[rowp[dst[e]] + rank[e]] = src[e] * 4 + etype[e];
}

// ---------------------------------------------------------------------------
// init: h = hinit = x @ W_in + b_in  -> h [M2][64] hi/lo + hin [M2][64] hi/lo
__global__ __launch_bounds__(256) void init_gemm(
    const ushort_t* __restrict__ xhi, const ushort_t* __restrict__ xlo,
    const ushort_t* __restrict__ Bh, const ushort_t* __restrict__ Bl,
    const float* __restrict__ b_in,
    ushort_t* __restrict__ h_hi, ushort_t* __restrict__ h_lo,
    ushort_t* __restrict__ hin_hi, ushort_t* __restrict__ hin_lo)
{
    __shared__ ushort_t lds[12288];
    ushort_t* LBh = lds;
    ushort_t* LBl = lds + 6144;
    const int tid = threadIdx.x, lane = tid & 63, wid = tid >> 6;
    const int lr = lane & 15, g = lane >> 4;
    stage_tile<12>(Bh, LBh, 64, tid, 256);
    stage_tile<12>(Bl, LBl, 64, tid, 256);
    __syncthreads();
    for (int wt = blockIdx.x * 4 + wid; wt < NTILES16; wt += gridDim.x * 4) {
        const ushort_t* pAh = xhi + (size_t)wt * 16 * 96;
        const ushort_t* pAl = xlo + (size_t)wt * 16 * 96;
        f32x4 acc[4];
        f32x4 zz = {0.f, 0.f, 0.f, 0.f};
#pragma unroll
        for (int f = 0; f < 4; ++f) acc[f] = zz;
#pragma unroll
        for (int ks = 0; ks < 3; ++ks) {
            int kg = ks * 4 + g;
            short8 ah = afrag(pAh, 96, lr, kg);
            short8 al = afrag(pAl, 96, lr, kg);
#pragma unroll
            for (int f = 0; f < 4; ++f) {
                short8 bh = rdfrag<12>(LBh, f * 16 + lr, kg);
                short8 bl = rdfrag<12>(LBl, f * 16 + lr, kg);
                acc[f] = MFMA(ah, bh, acc[f]);
                acc[f] = MFMA(ah, bl, acc[f]);
                acc[f] = MFMA(al, bh, acc[f]);
            }
        }
#pragma unroll
        for (int f = 0; f < 4; ++f) {
            int o = lr + f * 16;
            float b = b_in[o];
#pragma unroll
            for (int q = 0; q < 4; ++q) {
                int m = wt * 16 + g * 4 + q;
                if (m < N_NODES) {
                    float v = acc[f][q] + b;
                    split_store(h_hi, h_lo, (size_t)m * 64 + o, v);
                    split_store(hin_hi, hin_lo, (size_t)m * 64 + o, v);
                }
            }
        }
    }
}

// ---------------------------------------------------------------------------
// nt (single-bf16, 16-row tiles, 8 waves/block): ntr = relu(h @ edge_W + b)
// A = h_hi [M2][64]
__global__ __launch_bounds__(512, 2) void nt_gemm(
    const ushort_t* __restrict__ hhi,          // [M2][64]
    const ushort_t* __restrict__ Bh,           // BtE_hi [256][64]
    const float* __restrict__ edge_b, ushort_t* __restrict__ ntr)
{
    __shared__ ushort_t lds[16384];            // 32 KB
    const int tid = threadIdx.x, lane = tid & 63, wid = tid >> 6;
    const int lr = lane & 15, g = lane >> 4;
    stage_tile<8>(Bh, lds, 256, tid, 512);
    __syncthreads();
    for (int wt = blockIdx.x * 8 + wid; wt < NTILES16; wt += gridDim.x * 8) {
        const ushort_t* pA = hhi + (size_t)wt * 16 * 64;
        f32x4 acc[16];
        f32x4 zz = {0.f, 0.f, 0.f, 0.f};
#pragma unroll
        for (int f = 0; f < 16; ++f) acc[f] = zz;
#pragma unroll
        for (int ks = 0; ks < 2; ++ks) {
            int kg = ks * 4 + g;
            short8 ah = afrag(pA, 64, lr, kg);
#pragma unroll
            for (int f = 0; f < 16; ++f) {
                short8 bh = rdfrag<8>(lds, f * 16 + lr, kg);
                acc[f] = MFMA(ah, bh, acc[f]);
            }
        }
#pragma unroll
        for (int f = 0; f < 16; ++f) {
            int colg = lr + f * 16;
            float b = edge_b[colg >> 6];
#pragma unroll
            for (int q = 0; q < 4; ++q) {
                int m = wt * 16 + g * 4 + q;
                if (m < N_NODES) {
                    float v = fmaxf(acc[f][q] + b, 0.f);
                    ntr[(size_t)m * 256 + colg] = f2b(v);
                }
            }
        }
    }
}

// ---------------------------------------------------------------------------
// aggru: agg (into LDS, never global) + GRU, fused per 64-node block.
// 8 waves: AGG phase -> wave w sums rows w*8..w*8+7 into swizzled LDS tile;
// __syncthreads; GRU phase -> 4 row-tiles x 2 col-halves, A ks<2 from LDS agg,
// ks>=2 from global h. B hi-gates (48 KB) in LDS; n-lo B from global (L2-hot).
__global__ __launch_bounds__(512, 2) void aggru_gemm(
    const ushort_t* __restrict__ ntr, const int* __restrict__ rowp,
    const int* __restrict__ ss,
    const ushort_t* __restrict__ Xhi, const ushort_t* __restrict__ Xlo, // h [M2][64]
    const ushort_t* __restrict__ BtgHi,  // [2][96][128]
    const ushort_t* __restrict__ BtgLo,  // [2][32][128]
    const float* __restrict__ bih, const float* __restrict__ bhh,
    ushort_t* __restrict__ Yhi, ushort_t* __restrict__ Ylo)
{
    __shared__ ushort_t ldsB[24576];   // 48 KB: [192][128] hi gates (both halves)
    __shared__ ushort_t aggh[4096];    // 8 KB: [64][64] agg hi, swizzled
    __shared__ ushort_t aggl[4096];    // 8 KB: agg lo
    const int tid = threadIdx.x, lane = tid & 63, wid = tid >> 6;
    const int lr = lane & 15, g = lane >> 4;
    stage_tile<16>(BtgHi, ldsB, 192, tid, 512);

    // ---- AGG into LDS
    const int base = blockIdx.x * 64;
#pragma unroll 1
    for (int j = 0; j < 8; ++j) {
        int r = wid * 8 + j;
        int d = base + r;
        float acc = 0.f;
        if (d < N_NODES) {
            const int beg = rowp[d];
            const int end = rowp[d + 1];
            for (int p = beg; p < end; p += 16) {
                float v[16];
#pragma unroll
                for (int i = 0; i < 16; ++i) {
                    bool inb = (p + i) < end;
                    int rec = ss[inb ? (p + i) : beg];
                    rec = inb ? rec : PAD_REC;
                    v[i] = b2f(ntr[(size_t)rec * 64 + lane]);
                }
                float s0 = (v[0] + v[1]) + (v[2] + v[3]);
                float s1 = (v[4] + v[5]) + (v[6] + v[7]);
                float s2 = (v[8] + v[9]) + (v[10] + v[11]);
                float s3 = (v[12] + v[13]) + (v[14] + v[15]);
                acc += (s0 + s1) + (s2 + s3);
            }
        }
        int byt = (r * 128 + lane * 2) ^ ((r & 7) << 4);
        ushort_t hv = f2b(acc);
        *(ushort_t*)((char*)aggh + byt) = hv;
        *(ushort_t*)((char*)aggl + byt) = f2b(acc - b2f(hv));
    }
    __syncthreads();

    // ---- GRU
    const int rt = wid & 3, hh = wid >> 2;
    const int ooff = hh * 32;
    const int bb = hh * 96;                       // ldsB row base for col-half
    const int wt = blockIdx.x * 4 + rt;
    const ushort_t* pXh = Xhi + (size_t)wt * 16 * 64;
    const ushort_t* pXl = Xlo + (size_t)wt * 16 * 64;
    const ushort_t* pBln = BtgLo + (size_t)hh * 32 * 128;
    f32x4 aR[2], aZ[2], aIN[2], aHN[2];
    f32x4 zz = {0.f, 0.f, 0.f, 0.f};
#pragma unroll
    for (int f = 0; f < 2; ++f) { aR[f] = zz; aZ[f] = zz; aIN[f] = zz; aHN[f] = zz; }
#pragma unroll
    for (int ks = 0; ks < 4; ++ks) {
        int kg = ks * 4 + g;
        short8 ah, al;
        if (ks < 2) {
            int arow = rt * 16 + lr;
            ah = rdfrag<8>(aggh, arow, kg);
            al = rdfrag<8>(aggl, arow, kg);
        } else {
            ah = afrag(pXh, 64, lr, kg - 8);
            al = afrag(pXl, 64, lr, kg - 8);
        }
#pragma unroll
        for (int f = 0; f < 2; ++f) {
            short8 bhr = rdfrag<16>(ldsB, bb + f * 16 + lr, kg);
            aR[f] = MFMA(ah, bhr, aR[f]);
            aR[f] = MFMA(al, bhr, aR[f]);
            short8 bhz = rdfrag<16>(ldsB, bb + 32 + f * 16 + lr, kg);
            aZ[f] = MFMA(ah, bhz, aZ[f]);
            aZ[f] = MFMA(al, bhz, aZ[f]);
            short8 bhn = rdfrag<16>(ldsB, bb + 64 + f * 16 + lr, kg);
            short8 bln = afrag(pBln, 128, f * 16 + lr, kg);
            if (ks < 2) {
                aIN[f] = MFMA(ah, bhn, aIN[f]);
                aIN[f] = MFMA(al, bhn, aIN[f]);
                aIN[f] = MFMA(ah, bln, aIN[f]);
            } else {
                aHN[f] = MFMA(ah, bhn, aHN[f]);
                aHN[f] = MFMA(al, bhn, aHN[f]);
                aHN[f] = MFMA(ah, bln, aHN[f]);
            }
        }
    }
#pragma unroll
    for (int f = 0; f < 2; ++f) {
        int o = ooff + f * 16 + lr;
        float br = bih[o] + bhh[o];
        float bz = bih[64 + o] + bhh[64 + o];
        float bi_n = bih[128 + o];
        float bh_n = bhh[128 + o];
#pragma unroll
        for (int q = 0; q < 4; ++q) {
            int m = wt * 16 + g * 4 + q;
            if (m < N_NODES) {
                float r = sigm(aR[f][q] + br);
                float z = sigm(aZ[f][q] + bz);
                float inn = aIN[f][q] + bi_n;
                float hn = aHN[f][q] + bh_n;
                float nn = tanh_f(inn + r * hn);
                size_t hix = (size_t)m * 64 + o;
                float hp = b2f(Xhi[hix]) + b2f(Xlo[hix]);
                float hv = (1.f - z) * nn + z * hp;
                split_store(Yhi, Ylo, hix, hv);
            }
        }
    }
}

// ---------------------------------------------------------------------------
// mlp fused: hidden = relu([hinit,h]@W1+b1) in per-wave swizzled LDS tile,
// then out = tanh(hidden@W2+b2).
__global__ __launch_bounds__(256) void mlp_fused(
    const ushort_t* __restrict__ hin_hi, const ushort_t* __restrict__ hin_lo,
    const ushort_t* __restrict__ hhi, const ushort_t* __restrict__ hlo,  // [M2][64]
    const ushort_t* __restrict__ B1h, const ushort_t* __restrict__ B1l,
    const float* __restrict__ b1,
    const ushort_t* __restrict__ B2h, const ushort_t* __restrict__ B2l,
    const float* __restrict__ b2, float* __restrict__ out)
{
    __shared__ ushort_t l1h[8192];
    __shared__ ushort_t l1l[8192];
    __shared__ ushort_t l2h[4096];
    __shared__ ushort_t l2l[4096];
    __shared__ ushort_t th[4][1024];
    __shared__ ushort_t tl[4][1024];
    const int tid = threadIdx.x, lane = tid & 63, wid = tid >> 6;
    const int lr = lane & 15, g = lane >> 4;
    stage_tile<16>(B1h, l1h, 64, tid, 256);
    stage_tile<16>(B1l, l1l, 64, tid, 256);
    stage_tile<8>(B2h, l2h, 64, tid, 256);
    stage_tile<8>(B2l, l2l, 64, tid, 256);
    __syncthreads();
    char* myh = (char*)th[wid];
    char* myl = (char*)tl[wid];
    for (int wt = blockIdx.x * 4 + wid; wt < NTILES16; wt += gridDim.x * 4) {
        const ushort_t* pAh0 = hin_hi + (size_t)wt * 16 * 64;
        const ushort_t* pAl0 = hin_lo + (size_t)wt * 16 * 64;
        const ushort_t* pAh1 = hhi + (size_t)wt * 16 * 64;
        const ushort_t* pAl1 = hlo + (size_t)wt * 16 * 64;
        f32x4 acc[4];
        f32x4 zz = {0.f, 0.f, 0.f, 0.f};
#pragma unroll
        for (int f = 0; f < 4; ++f) acc[f] = zz;
#pragma unroll
        for (int ks = 0; ks < 4; ++ks) {
            int kg = ks * 4 + g;
            short8 ah, al;
            if (ks < 2) {
                ah = afrag(pAh0, 64, lr, kg);
                al = afrag(pAl0, 64, lr, kg);
            } else {
                ah = afrag(pAh1, 64, lr, kg - 8);
                al = afrag(pAl1, 64, lr, kg - 8);
            }
#pragma unroll
            for (int f = 0; f < 4; ++f) {
                short8 bh = rdfrag<16>(l1h, f * 16 + lr, kg);
                short8 bl = rdfrag<16>(l1l, f * 16 + lr, kg);
                acc[f] = MFMA(ah, bh, acc[f]);
                acc[f] = MFMA(ah, bl, acc[f]);
                acc[f] = MFMA(al, bh, acc[f]);
            }
        }
#pragma unroll
        for (int f = 0; f < 4; ++f) {
            int col = f * 16 + lr;
            float b = b1[col];
#pragma unroll
            for (int q = 0; q < 4; ++q) {
                int row = g * 4 + q;
                float v = fmaxf(acc[f][q] + b, 0.f);
                int byt = (row * 128 + col * 2) ^ ((row & 7) << 4);
                ushort_t hv = f2b(v);
                *(ushort_t*)(myh + byt) = hv;
                *(ushort_t*)(myl + byt) = f2b(v - b2f(hv));
            }
        }
        f32x4 acc2[4];
#pragma unroll
        for (int f = 0; f < 4; ++f) acc2[f] = zz;
#pragma unroll
        for (int ks = 0; ks < 2; ++ks) {
            int kg = ks * 4 + g;
            int byt = (lr * 128 + kg * 16) ^ ((lr & 7) << 4);
            short8 ah = *(const short8*)(myh + byt);
            short8 al = *(const short8*)(myl + byt);
#pragma unroll
            for (int f = 0; f < 4; ++f) {
                short8 bh = rdfrag<8>(l2h, f * 16 + lr, kg);
                short8 bl = rdfrag<8>(l2l, f * 16 + lr, kg);
                acc2[f] = MFMA(ah, bh, acc2[f]);
                acc2[f] = MFMA(ah, bl, acc2[f]);
                acc2[f] = MFMA(al, bh, acc2[f]);
            }
        }
#pragma unroll
        for (int f = 0; f < 4; ++f) {
            int o = lr + f * 16;
            float b = b2[o];
#pragma unroll
            for (int q = 0; q < 4; ++q) {
                int m = wt * 16 + g * 4 + q;
                if (m < N_NODES)
                    out[(size_t)m * 64 + o] = tanh_f(acc2[f][q] + b);
            }
        }
    }
}

// ---------------------------------------------------------------------------
extern "C" void kernel_launch(void* const* d_in, const int* in_sizes, int n_in,
                              void* d_out, int out_size, void* d_ws, size_t ws_size,
                              hipStream_t stream)
{
    const float* x      = (const float*)d_in[0];
    const int*   etype  = (const int*)  d_in[1];
    const int*   src    = (const int*)  d_in[2];
    const int*   dst    = (const int*)  d_in[3];
    const float* W_in   = (const float*)d_in[4];
    const float* b_in   = (const float*)d_in[5];
    const float* edge_W = (const float*)d_in[6];
    const float* edge_b = (const float*)d_in[7];
    const float* gWih   = (const float*)d_in[8];
    const float* gWhh   = (const float*)d_in[9];
    const float* gbih   = (const float*)d_in[10];
    const float* gbhh   = (const float*)d_in[11];
    const float* W1     = (const float*)d_in[12];
    const float* b1     = (const float*)d_in[13];
    const float* W2     = (const float*)d_in[14];
    const float* b2     = (const float*)d_in[15];
    float* out = (float*)d_out;

    char* ws = (char*)d_ws;
    // --- workspace layout (bytes) ---
    ushort_t* ntr    = (ushort_t*)(ws);               // M2*256 bf16 + pad row
    ushort_t* x_hi   = (ushort_t*)(ws);               // alias (init only)
    ushort_t* x_lo   = (ushort_t*)(ws + 9609216);
    int*      rank   = (int*)     (ws + 19660800);    // alias (CSR build only)
    ushort_t* hA_hi  = (ushort_t*)(ws + 25625088);    // each 6,406,144
    ushort_t* hA_lo  = (ushort_t*)(ws + 32031232);
    ushort_t* hB_hi  = (ushort_t*)(ws + 38437376);
    ushort_t* hB_lo  = (ushort_t*)(ws + 44843520);
    ushort_t* hin_hi = (ushort_t*)(ws + 51249664);
    ushort_t* hin_lo = (ushort_t*)(ws + 57655808);
    char* wbase = ws + 64061952;
    ushort_t* BtWin_hi = (ushort_t*)(wbase);          // 6144 elems
    ushort_t* BtWin_lo = (ushort_t*)(wbase + 12288);
    ushort_t* BtE_hi   = (ushort_t*)(wbase + 24576);  // 16384 elems
    ushort_t* BtgHi    = (ushort_t*)(wbase + 57344);  // 24576 elems [2][96][128]
    ushort_t* BtgLo    = (ushort_t*)(wbase + 106496); // 8192 elems [2][32][128]
    ushort_t* BtW1_hi  = (ushort_t*)(wbase + 122880); // 8192 elems
    ushort_t* BtW1_lo  = (ushort_t*)(wbase + 139264);
    ushort_t* BtW2_hi  = (ushort_t*)(wbase + 155648); // 4096 elems
    ushort_t* BtW2_lo  = (ushort_t*)(wbase + 163840);
    char* cbase = ws + 64233984;
    int* deg    = (int*)(cbase);                      // 200,192 B
    int* rowp   = (int*)(cbase + 200192);             // (N+1)*4
    int* ss     = (int*)(cbase + 400640);             // 3.2 MB
    int* bsum   = (int*)(cbase + 3600640);
    int* boff   = (int*)(cbase + 3601664);

    const int edge_tblocks = (N_EDGES + 255) / 256;   // 3125
    const int GB  = 782;   // 256-thread GEMM grid (4 waves): 3128 tiles
    const int GB8 = 512;   // nt grid (8 waves/block)
    ushort_t* ntr_pad = ntr + (size_t)M2 * 256;

    // weight prep + deg/pad zero + x split (single kernel, runs first)
    const int PREP_TOTAL = 117648 + M2 * 96;
    prep_w_kernel<<<(PREP_TOTAL + 255) / 256, 256, 0, stream>>>(
        W_in, edge_W, gWih, gWhh, W1, W2, x,
        BtWin_hi, BtWin_lo, BtE_hi, BtgHi, BtgLo,
        BtW1_hi, BtW1_lo, BtW2_hi, BtW2_lo,
        deg, ntr_pad, x_hi, x_lo);

    // CSR build
    degrank_kernel<<<edge_tblocks, 256, 0, stream>>>(dst, deg, rank);
    scan_p1<<<SCAN_NB, 256, 0, stream>>>(deg, bsum);
    scan_p2<<<1, 256, 0, stream>>>(bsum, boff, rowp);
    scan_p3<<<SCAN_NB, 256, 0, stream>>>(deg, boff, rowp);
    fill2_kernel<<<edge_tblocks, 256, 0, stream>>>(src, etype, dst, rowp, rank, ss);

    // init -> hA + hinit
    init_gemm<<<GB, 256, 0, stream>>>(x_hi, x_lo, BtWin_hi, BtWin_lo, b_in,
                                      hA_hi, hA_lo, hin_hi, hin_lo);

    ushort_t *Xhi = hA_hi, *Xlo = hA_lo, *Yhi = hB_hi, *Ylo = hB_lo;
    for (int s = 0; s < STEPS; ++s) {
        nt_gemm<<<GB8, 512, 0, stream>>>(Xhi, BtE_hi, edge_b, ntr);
        aggru_gemm<<<GB, 512, 0, stream>>>(ntr, rowp, ss, Xhi, Xlo,
                                           BtgHi, BtgLo, gbih, gbhh, Yhi, Ylo);
        ushort_t* t;
        t = Xhi; Xhi = Yhi; Yhi = t;
        t = Xlo; Xlo = Ylo; Ylo = t;
    }
    // after 4 steps final h is in hA (Xhi == hA_hi)

    mlp_fused<<<GB, 256, 0, stream>>>(hin_hi, hin_lo, Xhi, Xlo,
                                      BtW1_hi, BtW1_lo, b1,
                                      BtW2_hi, BtW2_lo, b2, out);
}

// Round 14
// 365.099 us; speedup vs baseline: 1.1019x; 1.1019x over previous
//
#include <hip/hip_runtime.h>
#include <hip/hip_bf16.h>

#define N_NODES 50000
#define M2      50048          // padded to multiple of 64
#define N_EDGES 800000
#define H 64
#define F 74
#define T 4
#define STEPS 4
#define NTILES16 (M2/16)       // 3128 wave-tiles of 16 rows
#define PAD_REC  (M2*4)        // zeroed pad row in ntr
#define SCAN_NB  196           // ceil(N_NODES/256)

using short8 = __attribute__((ext_vector_type(8))) short;
using f32x4  = __attribute__((ext_vector_type(4))) float;
typedef unsigned short ushort_t;

#define MFMA(a,b,c) __builtin_amdgcn_mfma_f32_16x16x32_bf16(a,b,c,0,0,0)

static __device__ inline float b2f(ushort_t u) {
    union { unsigned int i; float f; } c; c.i = ((unsigned int)u) << 16; return c.f;
}
static __device__ inline ushort_t f2b(float v) {
    union { __hip_bfloat16 b; ushort_t u; } c; c.b = __float2bfloat16(v); return c.u;
}
static __device__ inline void split_store(ushort_t* hi, ushort_t* lo, size_t ix, float v) {
    ushort_t h = f2b(v);
    hi[ix] = h;
    lo[ix] = f2b(v - b2f(h));
}
static __device__ inline float sigm(float x) { return 1.f / (1.f + __expf(-x)); }
static __device__ inline float tanh_f(float x) {
    float e2 = __expf(2.f * x); return 1.f - 2.f / (e2 + 1.f);
}

// ---- LDS staging of B-tiles (bf16, row-major [rows][KW8*8]) with XOR swizzle
template<int KW8>
static __device__ inline void stage_tile(const ushort_t* __restrict__ g, ushort_t* l,
                                         int rows, int tid, int nthr) {
    const int chunks = rows * KW8;
    for (int i = tid; i < chunks; i += nthr) {
        int row = i / KW8, kg = i - row * KW8;
        short8 v = *(const short8*)(g + (size_t)row * (KW8 * 8) + kg * 8);
        int b = (row * (KW8 * 16) + kg * 16) ^ ((row & 7) << 4);
        *(short8*)((char*)l + b) = v;
    }
}
template<int KW8>
static __device__ inline short8 rdfrag(const ushort_t* l, int row, int kg) {
    int b = (row * (KW8 * 16) + kg * 16) ^ ((row & 7) << 4);
    return *(const short8*)((const char*)l + b);
}
static __device__ inline short8 afrag(const ushort_t* base, int LD, int row, int kg) {
    return *(const short8*)(base + (size_t)row * LD + kg * 8);
}

// ---------------------------------------------------------------------------
// fused weight prep + deg-zero + ntr-pad-zero + x split (runs FIRST).
// ranges: [0,6144) Win | [6144,22528) E(hi) | [22528,55296) gru |
//   [55296,63488) W1 | [63488,67584) W2 | [67584,117584) deg=0 |
//   [117584,117648) ntr pad=0 | [117648,+M2*96) x split
// gru layout (round-11): [2 half][128 row][128 k]; row = g*32+cc,
// g:0=r-hi 1=z-hi 2=n-hi 3=n-lo; col = min(g,2)*64 + half*32 + cc.
__global__ __launch_bounds__(256) void prep_w_kernel(
    const float* __restrict__ W_in, const float* __restrict__ eW,
    const float* __restrict__ Wih, const float* __restrict__ Whh,
    const float* __restrict__ W1, const float* __restrict__ W2,
    const float* __restrict__ x,
    ushort_t* __restrict__ BtWin_hi, ushort_t* __restrict__ BtWin_lo,
    ushort_t* __restrict__ BtE_hi,
    ushort_t* __restrict__ Btg_all,
    ushort_t* __restrict__ BtW1_hi, ushort_t* __restrict__ BtW1_lo,
    ushort_t* __restrict__ BtW2_hi, ushort_t* __restrict__ BtW2_lo,
    int* __restrict__ deg, ushort_t* __restrict__ ntr_pad,
    ushort_t* __restrict__ x_hi, ushort_t* __restrict__ x_lo)
{
    int idx = blockIdx.x * 256 + threadIdx.x;
    if (idx < 6144) {                       // Win: [64 col][96 k]
        int col = idx / 96, k = idx - col * 96;
        float v = (k < F) ? W_in[(size_t)k * 64 + col] : 0.f;
        split_store(BtWin_hi, BtWin_lo, idx, v);
    } else if (idx < 22528) {               // E: [256 c][64 k], hi only
        int i = idx - 6144;
        int c = i >> 6, k = i & 63;
        float v = eW[(c >> 6) * 4096 + k * 64 + (c & 63)];
        BtE_hi[i] = f2b(v);
    } else if (idx < 55296) {               // gru: [2][128][128]
        int i = idx - 22528;
        int hh = i >> 14;
        int r2 = i & 16383;
        int rr = r2 >> 7, k = r2 & 127;
        int g = rr >> 5, cc = rr & 31;
        int gate = (g == 3) ? 2 : g;
        int col = gate * 64 + hh * 32 + cc;
        float v = (k < 64) ? Wih[(size_t)k * 192 + col]
                           : Whh[(size_t)(k - 64) * 192 + col];
        ushort_t h = f2b(v);
        Btg_all[i] = (g == 3) ? f2b(v - b2f(h)) : h;
    } else if (idx < 63488) {               // W1: [64 col][128 k]
        int i = idx - 55296;
        int col = i >> 7, k = i & 127;
        float v = W1[(size_t)k * 64 + col];
        split_store(BtW1_hi, BtW1_lo, i, v);
    } else if (idx < 67584) {               // W2: [64 col][64 k]
        int i = idx - 63488;
        int col = i >> 6, k = i & 63;
        float v = W2[(size_t)k * 64 + col];
        split_store(BtW2_hi, BtW2_lo, i, v);
    } else if (idx < 117584) {              // deg zero
        deg[idx - 67584] = 0;
    } else if (idx < 117648) {              // ntr pad row zero
        ntr_pad[idx - 117584] = 0;
    } else {                                // x split [M2][96]
        int i = idx - 117648;
        if (i < M2 * 96) {
            int row = i / 96, c = i - row * 96;
            float v = (row < N_NODES && c < F) ? x[(size_t)row * F + c] : 0.f;
            split_store(x_hi, x_lo, i, v);
        }
    }
}

// ---------------------------------------------------------------------------
// CSR build: one atomic pass (deg + rank), two-level scan, no-atomic scatter.
__global__ __launch_bounds__(256) void degrank_kernel(
    const int* __restrict__ dst, int* __restrict__ deg, int* __restrict__ rank)
{
    int e = blockIdx.x * 256 + threadIdx.x;
    if (e < N_EDGES) rank[e] = atomicAdd(&deg[dst[e]], 1);
}

__global__ __launch_bounds__(256) void scan_p1(
    const int* __restrict__ deg, int* __restrict__ bsum)
{
    __shared__ int ws4[4];
    const int tid = threadIdx.x, lane = tid & 63, w = tid >> 6;
    int idx = blockIdx.x * 256 + tid;
    int v = (idx < N_NODES) ? deg[idx] : 0;
#pragma unroll
    for (int off = 32; off >= 1; off >>= 1) v += __shfl_down(v, off, 64);
    if (lane == 0) ws4[w] = v;
    __syncthreads();
    if (tid == 0) bsum[blockIdx.x] = ws4[0] + ws4[1] + ws4[2] + ws4[3];
}

__global__ __launch_bounds__(256) void scan_p2(
    const int* __restrict__ bsum, int* __restrict__ boff, int* __restrict__ rowp)
{
    __shared__ int ws4[4];
    const int tid = threadIdx.x, lane = tid & 63, w = tid >> 6;
    int v = (tid < SCAN_NB) ? bsum[tid] : 0;
    int x = v;
#pragma unroll
    for (int off = 1; off < 64; off <<= 1) {
        int u = __shfl_up(x, off, 64);
        if (lane >= off) x += u;
    }
    if (lane == 63) ws4[w] = x;
    __syncthreads();
    int a0 = ws4[0], a1 = ws4[1], a2 = ws4[2];
    int add = (w > 0 ? a0 : 0) + (w > 1 ? a1 : 0) + (w > 2 ? a2 : 0);
    if (tid < SCAN_NB) boff[tid] = add + x - v;
    if (tid == 255) rowp[N_NODES] = add + x;
}

__global__ __launch_bounds__(256) void scan_p3(
    const int* __restrict__ deg, const int* __restrict__ boff,
    int* __restrict__ rowp)
{
    __shared__ int ws4[4];
    const int tid = threadIdx.x, lane = tid & 63, w = tid >> 6;
    int idx = blockIdx.x * 256 + tid;
    int v = (idx < N_NODES) ? deg[idx] : 0;
    int x = v;
#pragma unroll
    for (int off = 1; off < 64; off <<= 1) {
        int u = __shfl_up(x, off, 64);
        if (lane >= off) x += u;
    }
    if (lane == 63) ws4[w] = x;
    __syncthreads();
    int a0 = ws4[0], a1 = ws4[1], a2 = ws4[2];
    int add = boff[blockIdx.x]
            + (w > 0 ? a0 : 0) + (w > 1 ? a1 : 0) + (w > 2 ? a2 : 0);
    if (idx < N_NODES) rowp[idx] = add + x - v;
}

__global__ __launch_bounds__(256) void fill2_kernel(
    const int* __restrict__ src, const int* __restrict__ etype,
    const int* __restrict__ dst, const int* __restrict__ rowp,
    const int* __restrict__ rank, int* __restrict__ ss)
{
    int e = blockIdx.x * 256 + threadIdx.x;
    if (e < N_EDGES)
        ss[rowp[dst[e]] + rank[e]] = src[e] * 4 + etype[e];
}

// ---------------------------------------------------------------------------
// init: h = hinit = x @ W_in + b_in  -> h [M2][64] hi/lo + hin [M2][64] hi/lo
__global__ __launch_bounds__(256) void init_gemm(
    const ushort_t* __restrict__ xhi, const ushort_t* __restrict__ xlo,
    const ushort_t* __restrict__ Bh, const ushort_t* __restrict__ Bl,
    const float* __restrict__ b_in,
    ushort_t* __restrict__ h_hi, ushort_t* __restrict__ h_lo,
    ushort_t* __restrict__ hin_hi, ushort_t* __restrict__ hin_lo)
{
    __shared__ ushort_t lds[12288];
    ushort_t* LBh = lds;
    ushort_t* LBl = lds + 6144;
    const int tid = threadIdx.x, lane = tid & 63, wid = tid >> 6;
    const int lr = lane & 15, g = lane >> 4;
    stage_tile<12>(Bh, LBh, 64, tid, 256);
    stage_tile<12>(Bl, LBl, 64, tid, 256);
    __syncthreads();
    for (int wt = blockIdx.x * 4 + wid; wt < NTILES16; wt += gridDim.x * 4) {
        const ushort_t* pAh = xhi + (size_t)wt * 16 * 96;
        const ushort_t* pAl = xlo + (size_t)wt * 16 * 96;
        f32x4 acc[4];
        f32x4 zz = {0.f, 0.f, 0.f, 0.f};
#pragma unroll
        for (int f = 0; f < 4; ++f) acc[f] = zz;
#pragma unroll
        for (int ks = 0; ks < 3; ++ks) {
            int kg = ks * 4 + g;
            short8 ah = afrag(pAh, 96, lr, kg);
            short8 al = afrag(pAl, 96, lr, kg);
#pragma unroll
            for (int f = 0; f < 4; ++f) {
                short8 bh = rdfrag<12>(LBh, f * 16 + lr, kg);
                short8 bl = rdfrag<12>(LBl, f * 16 + lr, kg);
                acc[f] = MFMA(ah, bh, acc[f]);
                acc[f] = MFMA(ah, bl, acc[f]);
                acc[f] = MFMA(al, bh, acc[f]);
            }
        }
#pragma unroll
        for (int f = 0; f < 4; ++f) {
            int o = lr + f * 16;
            float b = b_in[o];
#pragma unroll
            for (int q = 0; q < 4; ++q) {
                int m = wt * 16 + g * 4 + q;
                if (m < N_NODES) {
                    float v = acc[f][q] + b;
                    split_store(h_hi, h_lo, (size_t)m * 64 + o, v);
                    split_store(hin_hi, hin_lo, (size_t)m * 64 + o, v);
                }
            }
        }
    }
}

// ---------------------------------------------------------------------------
// nt (single-bf16, 16-row tiles, 8 waves/block): ntr = relu(h @ edge_W + b)
__global__ __launch_bounds__(512, 2) void nt_gemm(
    const ushort_t* __restrict__ hhi,          // [M2][64]
    const ushort_t* __restrict__ Bh,           // BtE_hi [256][64]
    const float* __restrict__ edge_b, ushort_t* __restrict__ ntr)
{
    __shared__ ushort_t lds[16384];            // 32 KB
    const int tid = threadIdx.x, lane = tid & 63, wid = tid >> 6;
    const int lr = lane & 15, g = lane >> 4;
    stage_tile<8>(Bh, lds, 256, tid, 512);
    __syncthreads();
    for (int wt = blockIdx.x * 8 + wid; wt < NTILES16; wt += gridDim.x * 8) {
        const ushort_t* pA = hhi + (size_t)wt * 16 * 64;
        f32x4 acc[16];
        f32x4 zz = {0.f, 0.f, 0.f, 0.f};
#pragma unroll
        for (int f = 0; f < 16; ++f) acc[f] = zz;
#pragma unroll
        for (int ks = 0; ks < 2; ++ks) {
            int kg = ks * 4 + g;
            short8 ah = afrag(pA, 64, lr, kg);
#pragma unroll
            for (int f = 0; f < 16; ++f) {
                short8 bh = rdfrag<8>(lds, f * 16 + lr, kg);
                acc[f] = MFMA(ah, bh, acc[f]);
            }
        }
#pragma unroll
        for (int f = 0; f < 16; ++f) {
            int colg = lr + f * 16;
            float b = edge_b[colg >> 6];
#pragma unroll
            for (int q = 0; q < 4; ++q) {
                int m = wt * 16 + g * 4 + q;
                if (m < N_NODES) {
                    float v = fmaxf(acc[f][q] + b, 0.f);
                    ntr[(size_t)m * 256 + colg] = f2b(v);
                }
            }
        }
    }
}

// ---------------------------------------------------------------------------
// agg: wave per node, branchless 16-wide gather batches -> agg [M2][64] hi/lo
__global__ __launch_bounds__(256, 4) void agg_kernel(
    const ushort_t* __restrict__ ntr, const int* __restrict__ row_ptr,
    const int* __restrict__ ss, ushort_t* __restrict__ agg_hi,
    ushort_t* __restrict__ agg_lo)
{
    const int lane = threadIdx.x & 63;
    const int w = __builtin_amdgcn_readfirstlane((int)(threadIdx.x >> 6));
    const int d = blockIdx.x * 4 + w;
    if (d >= N_NODES) return;
    const int beg = row_ptr[d];
    const int end = row_ptr[d + 1];
    float acc = 0.f;
    for (int p = beg; p < end; p += 16) {
        float v[16];
#pragma unroll
        for (int i = 0; i < 16; ++i) {
            bool inb = (p + i) < end;
            int rec = ss[inb ? (p + i) : beg];
            rec = inb ? rec : PAD_REC;
            v[i] = b2f(ntr[(size_t)rec * 64 + lane]);
        }
        float s0 = (v[0] + v[1]) + (v[2] + v[3]);
        float s1 = (v[4] + v[5]) + (v[6] + v[7]);
        float s2 = (v[8] + v[9]) + (v[10] + v[11]);
        float s3 = (v[12] + v[13]) + (v[14] + v[15]);
        acc += (s0 + s1) + (s2 + s3);
    }
    split_store(agg_hi, agg_lo, (size_t)d * 64 + lane, acc);
}

// ---------------------------------------------------------------------------
// gru3 (persistent, round-11 structure): 8 waves = 4 row-tiles x 2 col-halves.
// All B in LDS ([2][128][128] = 64 KB); A split: agg (ks<2) and h (ks>=2),
// both slim [M2][64]. Writes h_next slim.
__global__ __launch_bounds__(512, 2) void gru3_gemm(
    const ushort_t* __restrict__ agg_hi, const ushort_t* __restrict__ agg_lo,
    const ushort_t* __restrict__ Xhi, const ushort_t* __restrict__ Xlo,
    const ushort_t* __restrict__ Btg,    // [2][128][128]
    const float* __restrict__ bih, const float* __restrict__ bhh,
    ushort_t* __restrict__ Yhi, ushort_t* __restrict__ Ylo)
{
    __shared__ ushort_t lds[32768];      // 64 KB (both halves)
    const int tid = threadIdx.x, lane = tid & 63, wid = tid >> 6;
    const int lr = lane & 15, g = lane >> 4;
    stage_tile<16>(Btg, lds, 256, tid, 512);   // flat [256][128]
    __syncthreads();
    const int hh = wid >> 2;
    const int ooff = hh * 32;
    const int bb = hh * 128;
    for (int wt0 = blockIdx.x * 4; wt0 < NTILES16; wt0 += gridDim.x * 4) {
        const int wt = wt0 + (wid & 3);
        const ushort_t* pGh = agg_hi + (size_t)wt * 16 * 64;
        const ushort_t* pGl = agg_lo + (size_t)wt * 16 * 64;
        const ushort_t* pXh = Xhi + (size_t)wt * 16 * 64;
        const ushort_t* pXl = Xlo + (size_t)wt * 16 * 64;
        f32x4 aR[2], aZ[2], aIN[2], aHN[2];
        f32x4 zz = {0.f, 0.f, 0.f, 0.f};
#pragma unroll
        for (int f = 0; f < 2; ++f) { aR[f] = zz; aZ[f] = zz; aIN[f] = zz; aHN[f] = zz; }
#pragma unroll
        for (int ks = 0; ks < 4; ++ks) {
            int kg = ks * 4 + g;
            short8 ah, al;
            if (ks < 2) {
                ah = afrag(pGh, 64, lr, kg);
                al = afrag(pGl, 64, lr, kg);
            } else {
                ah = afrag(pXh, 64, lr, kg - 8);
                al = afrag(pXl, 64, lr, kg - 8);
            }
#pragma unroll
            for (int f = 0; f < 2; ++f) {
                short8 bhr = rdfrag<16>(lds, bb + f * 16 + lr, kg);
                aR[f] = MFMA(ah, bhr, aR[f]);
                aR[f] = MFMA(al, bhr, aR[f]);
                short8 bhz = rdfrag<16>(lds, bb + 32 + f * 16 + lr, kg);
                aZ[f] = MFMA(ah, bhz, aZ[f]);
                aZ[f] = MFMA(al, bhz, aZ[f]);
                short8 bhn = rdfrag<16>(lds, bb + 64 + f * 16 + lr, kg);
                short8 bln = rdfrag<16>(lds, bb + 96 + f * 16 + lr, kg);
                if (ks < 2) {
                    aIN[f] = MFMA(ah, bhn, aIN[f]);
                    aIN[f] = MFMA(al, bhn, aIN[f]);
                    aIN[f] = MFMA(ah, bln, aIN[f]);
                } else {
                    aHN[f] = MFMA(ah, bhn, aHN[f]);
                    aHN[f] = MFMA(al, bhn, aHN[f]);
                    aHN[f] = MFMA(ah, bln, aHN[f]);
                }
            }
        }
#pragma unroll
        for (int f = 0; f < 2; ++f) {
            int o = ooff + f * 16 + lr;
            float br = bih[o] + bhh[o];
            float bz = bih[64 + o] + bhh[64 + o];
            float bi_n = bih[128 + o];
            float bh_n = bhh[128 + o];
#pragma unroll
            for (int q = 0; q < 4; ++q) {
                int m = wt * 16 + g * 4 + q;
                if (m < N_NODES) {
                    float r = sigm(aR[f][q] + br);
                    float z = sigm(aZ[f][q] + bz);
                    float inn = aIN[f][q] + bi_n;
                    float hn = aHN[f][q] + bh_n;
                    float nn = tanh_f(inn + r * hn);
                    size_t hix = (size_t)m * 64 + o;
                    float hp = b2f(Xhi[hix]) + b2f(Xlo[hix]);
                    float hv = (1.f - z) * nn + z * hp;
                    split_store(Yhi, Ylo, hix, hv);
                }
            }
        }
    }
}

// ---------------------------------------------------------------------------
// mlp fused: hidden = relu([hinit,h]@W1+b1) in per-wave swizzled LDS tile,
// then out = tanh(hidden@W2+b2).
__global__ __launch_bounds__(256) void mlp_fused(
    const ushort_t* __restrict__ hin_hi, const ushort_t* __restrict__ hin_lo,
    const ushort_t* __restrict__ hhi, const ushort_t* __restrict__ hlo,
    const ushort_t* __restrict__ B1h, const ushort_t* __restrict__ B1l,
    const float* __restrict__ b1,
    const ushort_t* __restrict__ B2h, const ushort_t* __restrict__ B2l,
    const float* __restrict__ b2, float* __restrict__ out)
{
    __shared__ ushort_t l1h[8192];
    __shared__ ushort_t l1l[8192];
    __shared__ ushort_t l2h[4096];
    __shared__ ushort_t l2l[4096];
    __shared__ ushort_t th[4][1024];
    __shared__ ushort_t tl[4][1024];
    const int tid = threadIdx.x, lane = tid & 63, wid = tid >> 6;
    const int lr = lane & 15, g = lane >> 4;
    stage_tile<16>(B1h, l1h, 64, tid, 256);
    stage_tile<16>(B1l, l1l, 64, tid, 256);
    stage_tile<8>(B2h, l2h, 64, tid, 256);
    stage_tile<8>(B2l, l2l, 64, tid, 256);
    __syncthreads();
    char* myh = (char*)th[wid];
    char* myl = (char*)tl[wid];
    for (int wt = blockIdx.x * 4 + wid; wt < NTILES16; wt += gridDim.x * 4) {
        const ushort_t* pAh0 = hin_hi + (size_t)wt * 16 * 64;
        const ushort_t* pAl0 = hin_lo + (size_t)wt * 16 * 64;
        const ushort_t* pAh1 = hhi + (size_t)wt * 16 * 64;
        const ushort_t* pAl1 = hlo + (size_t)wt * 16 * 64;
        f32x4 acc[4];
        f32x4 zz = {0.f, 0.f, 0.f, 0.f};
#pragma unroll
        for (int f = 0; f < 4; ++f) acc[f] = zz;
#pragma unroll
        for (int ks = 0; ks < 4; ++ks) {
            int kg = ks * 4 + g;
            short8 ah, al;
            if (ks < 2) {
                ah = afrag(pAh0, 64, lr, kg);
                al = afrag(pAl0, 64, lr, kg);
            } else {
                ah = afrag(pAh1, 64, lr, kg - 8);
                al = afrag(pAl1, 64, lr, kg - 8);
            }
#pragma unroll
            for (int f = 0; f < 4; ++f) {
                short8 bh = rdfrag<16>(l1h, f * 16 + lr, kg);
                short8 bl = rdfrag<16>(l1l, f * 16 + lr, kg);
                acc[f] = MFMA(ah, bh, acc[f]);
                acc[f] = MFMA(ah, bl, acc[f]);
                acc[f] = MFMA(al, bh, acc[f]);
            }
        }
#pragma unroll
        for (int f = 0; f < 4; ++f) {
            int col = f * 16 + lr;
            float b = b1[col];
#pragma unroll
            for (int q = 0; q < 4; ++q) {
                int row = g * 4 + q;
                float v = fmaxf(acc[f][q] + b, 0.f);
                int byt = (row * 128 + col * 2) ^ ((row & 7) << 4);
                ushort_t hv = f2b(v);
                *(ushort_t*)(myh + byt) = hv;
                *(ushort_t*)(myl + byt) = f2b(v - b2f(hv));
            }
        }
        f32x4 acc2[4];
#pragma unroll
        for (int f = 0; f < 4; ++f) acc2[f] = zz;
#pragma unroll
        for (int ks = 0; ks < 2; ++ks) {
            int kg = ks * 4 + g;
            int byt = (lr * 128 + kg * 16) ^ ((lr & 7) << 4);
            short8 ah = *(const short8*)(myh + byt);
            short8 al = *(const short8*)(myl + byt);
#pragma unroll
            for (int f = 0; f < 4; ++f) {
                short8 bh = rdfrag<8>(l2h, f * 16 + lr, kg);
                short8 bl = rdfrag<8>(l2l, f * 16 + lr, kg);
                acc2[f] = MFMA(ah, bh, acc2[f]);
                acc2[f] = MFMA(ah, bl, acc2[f]);
                acc2[f] = MFMA(al, bh, acc2[f]);
            }
        }
#pragma unroll
        for (int f = 0; f < 4; ++f) {
            int o = lr + f * 16;
            float b = b2[o];
#pragma unroll
            for (int q = 0; q < 4; ++q) {
                int m = wt * 16 + g * 4 + q;
                if (m < N_NODES)
                    out[(size_t)m * 64 + o] = tanh_f(acc2[f][q] + b);
            }
        }
    }
}

// ---------------------------------------------------------------------------
extern "C" void kernel_launch(void* const* d_in, const int* in_sizes, int n_in,
                              void* d_out, int out_size, void* d_ws, size_t ws_size,
                              hipStream_t stream)
{
    const float* x      = (const float*)d_in[0];
    const int*   etype  = (const int*)  d_in[1];
    const int*   src    = (const int*)  d_in[2];
    const int*   dst    = (const int*)  d_in[3];
    const float* W_in   = (const float*)d_in[4];
    const float* b_in   = (const float*)d_in[5];
    const float* edge_W = (const float*)d_in[6];
    const float* edge_b = (const float*)d_in[7];
    const float* gWih   = (const float*)d_in[8];
    const float* gWhh   = (const float*)d_in[9];
    const float* gbih   = (const float*)d_in[10];
    const float* gbhh   = (const float*)d_in[11];
    const float* W1     = (const float*)d_in[12];
    const float* b1     = (const float*)d_in[13];
    const float* W2     = (const float*)d_in[14];
    const float* b2     = (const float*)d_in[15];
    float* out = (float*)d_out;

    char* ws = (char*)d_ws;
    // --- workspace layout (bytes) ---
    ushort_t* ntr    = (ushort_t*)(ws);               // M2*256 bf16 + pad row
    ushort_t* x_hi   = (ushort_t*)(ws);               // alias (init only)
    ushort_t* x_lo   = (ushort_t*)(ws + 9609216);
    int*      rank   = (int*)     (ws + 19660800);    // alias (CSR build only)
    ushort_t* hA_hi  = (ushort_t*)(ws + 25625088);    // each 6,406,144
    ushort_t* hA_lo  = (ushort_t*)(ws + 32031232);
    ushort_t* hB_hi  = (ushort_t*)(ws + 38437376);
    ushort_t* hB_lo  = (ushort_t*)(ws + 44843520);
    ushort_t* hin_hi = (ushort_t*)(ws + 51249664);
    ushort_t* hin_lo = (ushort_t*)(ws + 57655808);
    ushort_t* agg_hi = (ushort_t*)(ws + 64061952);
    ushort_t* agg_lo = (ushort_t*)(ws + 70468096);
    char* wbase = ws + 76874240;
    ushort_t* BtWin_hi = (ushort_t*)(wbase);          // 6144 elems
    ushort_t* BtWin_lo = (ushort_t*)(wbase + 12288);
    ushort_t* BtE_hi   = (ushort_t*)(wbase + 24576);  // 16384 elems
    ushort_t* Btg_all  = (ushort_t*)(wbase + 57344);  // 32768 elems [2][128][128]
    ushort_t* BtW1_hi  = (ushort_t*)(wbase + 122880); // 8192 elems
    ushort_t* BtW1_lo  = (ushort_t*)(wbase + 139264);
    ushort_t* BtW2_hi  = (ushort_t*)(wbase + 155648); // 4096 elems
    ushort_t* BtW2_lo  = (ushort_t*)(wbase + 163840);
    char* cbase = ws + 77046272;
    int* deg    = (int*)(cbase);                      // 200,192 B
    int* rowp   = (int*)(cbase + 200192);             // (N+1)*4
    int* ss     = (int*)(cbase + 400640);             // 3.2 MB
    int* bsum   = (int*)(cbase + 3600640);
    int* boff   = (int*)(cbase + 3601664);

    const int edge_tblocks = (N_EDGES + 255) / 256;   // 3125
    const int agg_blocks = (N_NODES + 3) / 4;         // 12500
    const int GB  = 782;   // 256-thread GEMM grid (4 waves): 3128 tiles
    const int GB8 = 512;   // nt grid (8 waves/block)
    const int GBF = 512;   // gru3 persistent grid
    ushort_t* ntr_pad = ntr + (size_t)M2 * 256;

    // weight prep + deg/pad zero + x split (single kernel, runs first)
    const int PREP_TOTAL = 117648 + M2 * 96;
    prep_w_kernel<<<(PREP_TOTAL + 255) / 256, 256, 0, stream>>>(
        W_in, edge_W, gWih, gWhh, W1, W2, x,
        BtWin_hi, BtWin_lo, BtE_hi, Btg_all,
        BtW1_hi, BtW1_lo, BtW2_hi, BtW2_lo,
        deg, ntr_pad, x_hi, x_lo);

    // CSR build
    degrank_kernel<<<edge_tblocks, 256, 0, stream>>>(dst, deg, rank);
    scan_p1<<<SCAN_NB, 256, 0, stream>>>(deg, bsum);
    scan_p2<<<1, 256, 0, stream>>>(bsum, boff, rowp);
    scan_p3<<<SCAN_NB, 256, 0, stream>>>(deg, boff, rowp);
    fill2_kernel<<<edge_tblocks, 256, 0, stream>>>(src, etype, dst, rowp, rank, ss);

    // init -> hA + hinit
    init_gemm<<<GB, 256, 0, stream>>>(x_hi, x_lo, BtWin_hi, BtWin_lo, b_in,
                                      hA_hi, hA_lo, hin_hi, hin_lo);

    ushort_t *Xhi = hA_hi, *Xlo = hA_lo, *Yhi = hB_hi, *Ylo = hB_lo;
    for (int s = 0; s < STEPS; ++s) {
        nt_gemm<<<GB8, 512, 0, stream>>>(Xhi, BtE_hi, edge_b, ntr);
        agg_kernel<<<agg_blocks, 256, 0, stream>>>(ntr, rowp, ss, agg_hi, agg_lo);
        gru3_gemm<<<GBF, 512, 0, stream>>>(agg_hi, agg_lo, Xhi, Xlo,
                                           Btg_all, gbih, gbhh, Yhi, Ylo);
        ushort_t* t;
        t = Xhi; Xhi = Yhi; Yhi = t;
        t = Xlo; Xlo = Ylo; Ylo = t;
    }
    // after 4 steps final h is in hA (Xhi == hA_hi)

    mlp_fused<<<GB, 256, 0, stream>>>(hin_hi, hin_lo, Xhi, Xlo,
                                      BtW1_hi, BtW1_lo, b1,
                                      BtW2_hi, BtW2_lo, b2, out);
}